// Round 1
// baseline (1941.080 us; speedup 1.0000x reference)
//
#include <hip/hip_runtime.h>
#include <math.h>

#define NNODES 100000
#define NEDGES 1600000

// ----------------------------- CSR build -----------------------------
__global__ void k_hist(const int* __restrict__ ei, int* __restrict__ deg, int E) {
  int e = blockIdx.x * blockDim.x + threadIdx.x;
  if (e < E) atomicAdd(&deg[ei[E + e]], 1);
}

__global__ __launch_bounds__(1024) void k_scan(const int* __restrict__ deg,
                                               int* __restrict__ offsets, int n) {
  __shared__ int sums[1024];
  int t = threadIdx.x;
  int chunk = (n + 1023) / 1024;
  int start = t * chunk;
  int end = min(start + chunk, n);
  int local = 0;
  for (int i = start; i < end; i++) local += deg[i];
  sums[t] = local;
  __syncthreads();
  for (int off = 1; off < 1024; off <<= 1) {
    int v = (t >= off) ? sums[t - off] : 0;
    __syncthreads();
    sums[t] += v;
    __syncthreads();
  }
  int run = sums[t] - local;  // exclusive prefix
  for (int i = start; i < end; i++) { offsets[i] = run; run += deg[i]; }
  if (t == 1023) offsets[n] = sums[1023];
}

__global__ void k_fill(const int* __restrict__ ei, const int* __restrict__ offsets,
                       int* __restrict__ cursor, int* __restrict__ csr_src, int E) {
  int e = blockIdx.x * blockDim.x + threadIdx.x;
  if (e >= E) return;
  int dst = ei[E + e];
  int slot = offsets[dst] + atomicAdd(&cursor[dst], 1);
  csr_src[slot] = ei[e];
}

// ----------------------------- SGEMM (fp32) -----------------------------
// C[n,M] = A[n,K] @ W[K,M].  64x64 tile, 256 threads, 4x4 per thread.
__global__ __launch_bounds__(256) void k_sgemm(const float* __restrict__ A,
                                               const float* __restrict__ W,
                                               float* __restrict__ C,
                                               int nrows, int K, int M) {
  __shared__ float As[16][68];
  __shared__ float Ws[16][68];
  const int tx = threadIdx.x & 15, ty = threadIdx.x >> 4;
  const int row0 = blockIdx.x * 64, col0 = blockIdx.y * 64;
  float acc[4][4] = {};
  for (int k0 = 0; k0 < K; k0 += 16) {
#pragma unroll
    for (int i = 0; i < 4; i++) {
      int lin = threadIdx.x + i * 256;
      int kk = lin & 15, r = lin >> 4;
      int row = row0 + r;
      As[kk][r] = (row < nrows) ? A[(size_t)row * K + k0 + kk] : 0.f;
    }
#pragma unroll
    for (int i = 0; i < 4; i++) {
      int lin = threadIdx.x + i * 256;
      int c = lin & 63, kk = lin >> 6;
      int col = col0 + c;
      Ws[kk][c] = (col < M) ? W[(size_t)(k0 + kk) * M + col] : 0.f;
    }
    __syncthreads();
#pragma unroll
    for (int kk = 0; kk < 16; kk++) {
      float4 w4 = *(const float4*)&Ws[kk][tx * 4];
      float4 a4 = *(const float4*)&As[kk][ty * 4];
      acc[0][0] += a4.x * w4.x; acc[0][1] += a4.x * w4.y; acc[0][2] += a4.x * w4.z; acc[0][3] += a4.x * w4.w;
      acc[1][0] += a4.y * w4.x; acc[1][1] += a4.y * w4.y; acc[1][2] += a4.y * w4.z; acc[1][3] += a4.y * w4.w;
      acc[2][0] += a4.z * w4.x; acc[2][1] += a4.z * w4.y; acc[2][2] += a4.z * w4.z; acc[2][3] += a4.z * w4.w;
      acc[3][0] += a4.w * w4.x; acc[3][1] += a4.w * w4.y; acc[3][2] += a4.w * w4.z; acc[3][3] += a4.w * w4.w;
    }
    __syncthreads();
  }
#pragma unroll
  for (int i = 0; i < 4; i++) {
    int row = row0 + ty * 4 + i;
    if (row >= nrows) continue;
#pragma unroll
    for (int j = 0; j < 4; j++) {
      int col = col0 + tx * 4 + j;
      if (col < M) C[(size_t)row * M + col] = acc[i][j];
    }
  }
}

// ----------------------------- SAGE aggregate -----------------------------
// out[v] = relu( mean_{e->v} hl[src[e]] + bias + hr[v] ), one wave per node.
__global__ __launch_bounds__(256) void k_sage_agg(const float* __restrict__ hl,
                                                  const float* __restrict__ hr,
                                                  const float* __restrict__ bias,
                                                  const int* __restrict__ offsets,
                                                  const int* __restrict__ csr_src,
                                                  float* __restrict__ out, int n, int F) {
  int wave = threadIdx.x >> 6, lane = threadIdx.x & 63;
  int v = blockIdx.x * 4 + wave;
  if (v >= n || lane >= F) return;
  int d0 = offsets[v], d1 = offsets[v + 1];
  float acc = 0.f;
  for (int e = d0; e < d1; e++) {
    int s = csr_src[e];
    acc += hl[(size_t)s * F + lane];
  }
  int d = d1 - d0;
  float inv = 1.f / (float)(d > 1 ? d : 1);
  float y = acc * inv + bias[lane] + hr[(size_t)v * F + lane];
  out[(size_t)v * F + lane] = fmaxf(y, 0.f);
}

// ----------------------------- GAT per-node attention scores -----------------------------
// als[v,h] = sum_c xh[v,h,c]*a_src[h,c];  ald likewise. One wave per node, lane -> 4 channels.
__global__ __launch_bounds__(256) void k_gat_score(const float* __restrict__ xh,
                                                   const float* __restrict__ a_s,
                                                   const float* __restrict__ a_d,
                                                   float* __restrict__ als,
                                                   float* __restrict__ ald, int n, int F) {
  int wave = threadIdx.x >> 6, lane = threadIdx.x & 63;
  int v = blockIdx.x * 4 + wave;
  if (v >= n || lane >= F) return;
  int lph = F >> 2;            // lanes per head
  int h = lane / lph;
  int c0 = lane * 4;           // channel in [0,4F)
  int cc = c0 - h * F;         // within-head channel
  float4 x4 = *(const float4*)&xh[(size_t)v * 4 * F + c0];
  float4 s4 = *(const float4*)&a_s[h * F + cc];
  float4 d4 = *(const float4*)&a_d[h * F + cc];
  float ps = x4.x * s4.x + x4.y * s4.y + x4.z * s4.z + x4.w * s4.w;
  float pd = x4.x * d4.x + x4.y * d4.y + x4.z * d4.z + x4.w * d4.w;
  for (int m = 1; m < lph; m <<= 1) { ps += __shfl_xor(ps, m); pd += __shfl_xor(pd, m); }
  if ((lane & (lph - 1)) == 0) { als[v * 4 + h] = ps; ald[v * 4 + h] = pd; }
}

// ----------------------------- GAT edge softmax -----------------------------
// alpha[e,h] = exp(lrelu(als[src]+ald[dst]) - max)/ (sum + 1e-16). One wave per dst node.
__global__ __launch_bounds__(256) void k_gat_edge(const float* __restrict__ als,
                                                  const float* __restrict__ ald,
                                                  const int* __restrict__ offsets,
                                                  const int* __restrict__ csr_src,
                                                  float* __restrict__ alpha, int n) {
  int wave = threadIdx.x >> 6, lane = threadIdx.x & 63;
  int v = blockIdx.x * 4 + wave;
  if (v >= n) return;
  int d0 = offsets[v], d1 = offsets[v + 1];
  float4 ad4 = *(const float4*)&ald[v * 4];
  float m0 = -1e30f, m1 = -1e30f, m2 = -1e30f, m3 = -1e30f;
  for (int e = d0 + lane; e < d1; e += 64) {
    int s = csr_src[e];
    float4 as4 = *(const float4*)&als[s * 4];
    float e0 = as4.x + ad4.x; e0 = e0 > 0.f ? e0 : 0.2f * e0;
    float e1 = as4.y + ad4.y; e1 = e1 > 0.f ? e1 : 0.2f * e1;
    float e2 = as4.z + ad4.z; e2 = e2 > 0.f ? e2 : 0.2f * e2;
    float e3 = as4.w + ad4.w; e3 = e3 > 0.f ? e3 : 0.2f * e3;
    *(float4*)&alpha[(size_t)e * 4] = make_float4(e0, e1, e2, e3);
    m0 = fmaxf(m0, e0); m1 = fmaxf(m1, e1); m2 = fmaxf(m2, e2); m3 = fmaxf(m3, e3);
  }
  for (int mm = 1; mm < 64; mm <<= 1) {
    m0 = fmaxf(m0, __shfl_xor(m0, mm));
    m1 = fmaxf(m1, __shfl_xor(m1, mm));
    m2 = fmaxf(m2, __shfl_xor(m2, mm));
    m3 = fmaxf(m3, __shfl_xor(m3, mm));
  }
  float s0 = 0.f, s1 = 0.f, s2 = 0.f, s3 = 0.f;
  for (int e = d0 + lane; e < d1; e += 64) {
    float4 e4 = *(const float4*)&alpha[(size_t)e * 4];
    float p0 = __expf(e4.x - m0);
    float p1 = __expf(e4.y - m1);
    float p2 = __expf(e4.z - m2);
    float p3 = __expf(e4.w - m3);
    *(float4*)&alpha[(size_t)e * 4] = make_float4(p0, p1, p2, p3);
    s0 += p0; s1 += p1; s2 += p2; s3 += p3;
  }
  for (int mm = 1; mm < 64; mm <<= 1) {
    s0 += __shfl_xor(s0, mm);
    s1 += __shfl_xor(s1, mm);
    s2 += __shfl_xor(s2, mm);
    s3 += __shfl_xor(s3, mm);
  }
  float i0 = 1.f / (s0 + 1e-16f), i1 = 1.f / (s1 + 1e-16f);
  float i2 = 1.f / (s2 + 1e-16f), i3 = 1.f / (s3 + 1e-16f);
  for (int e = d0 + lane; e < d1; e += 64) {
    float4 p4 = *(const float4*)&alpha[(size_t)e * 4];
    p4.x *= i0; p4.y *= i1; p4.z *= i2; p4.w *= i3;
    *(float4*)&alpha[(size_t)e * 4] = p4;
  }
}

// ----------------------------- GAT aggregate + bias + relu + head-mean -----------------------------
// One wave per node. lane handles channels [lane*4, lane*4+4) of the 4F concat output.
__global__ __launch_bounds__(256) void k_gat_agg(const float* __restrict__ xh,
                                                 const float* __restrict__ alpha,
                                                 const float* __restrict__ bias,
                                                 const int* __restrict__ offsets,
                                                 const int* __restrict__ csr_src,
                                                 float* __restrict__ out, int n, int F) {
  int wave = threadIdx.x >> 6, lane = threadIdx.x & 63;
  int v = blockIdx.x * 4 + wave;
  if (v >= n || lane >= F) return;
  int lph = F >> 2;
  int h = lane / lph;
  int c0 = lane * 4;
  int d0 = offsets[v], d1 = offsets[v + 1];
  float a0 = 0.f, a1 = 0.f, a2 = 0.f, a3 = 0.f;
  for (int e = d0; e < d1; e++) {
    int s = csr_src[e];
    float al = alpha[(size_t)e * 4 + h];
    float4 x4 = *(const float4*)&xh[(size_t)s * 4 * F + c0];
    a0 += al * x4.x; a1 += al * x4.y; a2 += al * x4.z; a3 += al * x4.w;
  }
  float4 b4 = *(const float4*)&bias[c0];
  a0 = fmaxf(a0 + b4.x, 0.f);
  a1 = fmaxf(a1 + b4.y, 0.f);
  a2 = fmaxf(a2 + b4.z, 0.f);
  a3 = fmaxf(a3 + b4.w, 0.f);
  // mean over heads: combine lanes that hold the same within-head channel
  for (int mm = lph; mm < F; mm <<= 1) {
    a0 += __shfl_xor(a0, mm);
    a1 += __shfl_xor(a1, mm);
    a2 += __shfl_xor(a2, mm);
    a3 += __shfl_xor(a3, mm);
  }
  if (lane < lph) {
    float4 o = make_float4(a0 * 0.25f, a1 * 0.25f, a2 * 0.25f, a3 * 0.25f);
    *(float4*)&out[(size_t)v * F + c0] = o;
  }
}

// ----------------------------- penalty + exp scale + L2 normalize -----------------------------
__global__ __launch_bounds__(256) void k_final(const float* __restrict__ y,
                                               const float* __restrict__ Wp,
                                               const float* __restrict__ bp,
                                               float* __restrict__ out, int n) {
  int wave = threadIdx.x >> 6, lane = threadIdx.x & 63;
  int v = blockIdx.x * 4 + wave;
  if (v >= n || lane >= 32) return;
  float yv = y[(size_t)v * 32 + lane];
  float p = yv * Wp[lane];
  for (int m = 1; m < 32; m <<= 1) p += __shfl_xor(p, m);
  p += bp[0];
  float s = __expf(p);
  float xv = yv * s;
  float q = xv * xv;
  for (int m = 1; m < 32; m <<= 1) q += __shfl_xor(q, m);
  float nrm = sqrtf(q);
  nrm = fmaxf(nrm, 1e-12f);
  out[(size_t)v * 32 + lane] = xv / nrm;
}

// ----------------------------- launch -----------------------------
extern "C" void kernel_launch(void* const* d_in, const int* in_sizes, int n_in,
                              void* d_out, int out_size, void* d_ws, size_t ws_size,
                              hipStream_t stream) {
  (void)in_sizes; (void)n_in; (void)out_size; (void)ws_size;
  const float* x   = (const float*)d_in[0];
  const int*   ei  = (const int*)d_in[1];
  const float* W1l = (const float*)d_in[2];
  const float* b1l = (const float*)d_in[3];
  const float* W1r = (const float*)d_in[4];
  const float* Wa1 = (const float*)d_in[5];
  const float* as1 = (const float*)d_in[6];
  const float* ad1 = (const float*)d_in[7];
  const float* ba1 = (const float*)d_in[8];
  const float* W2l = (const float*)d_in[9];
  const float* b2l = (const float*)d_in[10];
  const float* W2r = (const float*)d_in[11];
  const float* Wa2 = (const float*)d_in[12];
  const float* as2 = (const float*)d_in[13];
  const float* ad2 = (const float*)d_in[14];
  const float* ba2 = (const float*)d_in[15];
  const float* W3l = (const float*)d_in[16];
  const float* b3l = (const float*)d_in[17];
  const float* W3r = (const float*)d_in[18];
  const float* Wa3 = (const float*)d_in[19];
  const float* as3 = (const float*)d_in[20];
  const float* ad3 = (const float*)d_in[21];
  const float* ba3 = (const float*)d_in[22];
  const float* Wp  = (const float*)d_in[23];
  const float* bp  = (const float*)d_in[24];
  float* out = (float*)d_out;

  char* ws = (char*)d_ws;
  size_t off = 0;
  auto alloc = [&](size_t bytes) -> void* {
    void* p = ws + off;
    off += (bytes + 255) & ~(size_t)255;
    return p;
  };
  int* deg    = (int*)alloc((size_t)NNODES * 4);
  int* offs   = (int*)alloc((size_t)(NNODES + 1) * 4);
  int* cursor = (int*)alloc((size_t)NNODES * 4);
  int* csr    = (int*)alloc((size_t)NEDGES * 4);
  float* bufA  = (float*)alloc((size_t)NNODES * 256 * 4);  // xh
  float* bufB  = (float*)alloc((size_t)NNODES * 64 * 4);   // layer io
  float* bufC  = (float*)alloc((size_t)NNODES * 64 * 4);   // h_l
  float* bufD  = (float*)alloc((size_t)NNODES * 64 * 4);   // h_r
  float* alpha = (float*)alloc((size_t)NEDGES * 4 * 4);
  float* als   = (float*)alloc((size_t)NNODES * 4 * 4);
  float* ald   = (float*)alloc((size_t)NNODES * 4 * 4);

  hipMemsetAsync(deg, 0, (size_t)NNODES * 4, stream);
  hipMemsetAsync(cursor, 0, (size_t)NNODES * 4, stream);
  int eb = (NEDGES + 255) / 256;
  k_hist<<<eb, 256, 0, stream>>>(ei, deg, NEDGES);
  k_scan<<<1, 1024, 0, stream>>>(deg, offs, NNODES);
  k_fill<<<eb, 256, 0, stream>>>(ei, offs, cursor, csr, NEDGES);

  int nb = (NNODES + 3) / 4;
  auto gemm = [&](const float* A, const float* W, float* C, int K, int M) {
    dim3 grid((NNODES + 63) / 64, (M + 63) / 64);
    k_sgemm<<<grid, 256, 0, stream>>>(A, W, C, NNODES, K, M);
  };

  // ---- block 1 (in=128, F=64) ----
  gemm(x, W1l, bufC, 128, 64);
  gemm(x, W1r, bufD, 128, 64);
  k_sage_agg<<<nb, 256, 0, stream>>>(bufC, bufD, b1l, offs, csr, bufB, NNODES, 64);
  gemm(bufB, Wa1, bufA, 64, 256);
  k_gat_score<<<nb, 256, 0, stream>>>(bufA, as1, ad1, als, ald, NNODES, 64);
  k_gat_edge<<<nb, 256, 0, stream>>>(als, ald, offs, csr, alpha, NNODES);
  k_gat_agg<<<nb, 256, 0, stream>>>(bufA, alpha, ba1, offs, csr, bufB, NNODES, 64);

  // ---- block 2 (in=64, F=64) ----
  gemm(bufB, W2l, bufC, 64, 64);
  gemm(bufB, W2r, bufD, 64, 64);
  k_sage_agg<<<nb, 256, 0, stream>>>(bufC, bufD, b2l, offs, csr, bufB, NNODES, 64);
  gemm(bufB, Wa2, bufA, 64, 256);
  k_gat_score<<<nb, 256, 0, stream>>>(bufA, as2, ad2, als, ald, NNODES, 64);
  k_gat_edge<<<nb, 256, 0, stream>>>(als, ald, offs, csr, alpha, NNODES);
  k_gat_agg<<<nb, 256, 0, stream>>>(bufA, alpha, ba2, offs, csr, bufB, NNODES, 64);

  // ---- block 3 (in=64, F=32) ----
  gemm(bufB, W3l, bufC, 64, 32);
  gemm(bufB, W3r, bufD, 64, 32);
  k_sage_agg<<<nb, 256, 0, stream>>>(bufC, bufD, b3l, offs, csr, bufB, NNODES, 32);
  gemm(bufB, Wa3, bufA, 32, 128);
  k_gat_score<<<nb, 256, 0, stream>>>(bufA, as3, ad3, als, ald, NNODES, 32);
  k_gat_edge<<<nb, 256, 0, stream>>>(als, ald, offs, csr, alpha, NNODES);
  k_gat_agg<<<nb, 256, 0, stream>>>(bufA, alpha, ba3, offs, csr, bufB, NNODES, 32);

  k_final<<<nb, 256, 0, stream>>>(bufB, Wp, bp, out, NNODES);
}

// Round 2
// 1671.908 us; speedup vs baseline: 1.1610x; 1.1610x over previous
//
#include <hip/hip_runtime.h>
#include <math.h>

#define NNODES 100000
#define NEDGES 1600000

// ----------------------------- CSR build -----------------------------
__global__ void k_hist(const int* __restrict__ ei, int* __restrict__ deg, int E) {
  int e = blockIdx.x * blockDim.x + threadIdx.x;
  if (e < E) atomicAdd(&deg[ei[E + e]], 1);
}

__global__ __launch_bounds__(1024) void k_scan(const int* __restrict__ deg,
                                               int* __restrict__ offsets, int n) {
  __shared__ int sums[1024];
  int t = threadIdx.x;
  int chunk = (n + 1023) / 1024;
  int start = t * chunk;
  int end = min(start + chunk, n);
  int local = 0;
  for (int i = start; i < end; i++) local += deg[i];
  sums[t] = local;
  __syncthreads();
  for (int off = 1; off < 1024; off <<= 1) {
    int v = (t >= off) ? sums[t - off] : 0;
    __syncthreads();
    sums[t] += v;
    __syncthreads();
  }
  int run = sums[t] - local;  // exclusive prefix
  for (int i = start; i < end; i++) { offsets[i] = run; run += deg[i]; }
  if (t == 1023) offsets[n] = sums[1023];
}

__global__ void k_fill(const int* __restrict__ ei, const int* __restrict__ offsets,
                       int* __restrict__ cursor, int* __restrict__ csr_src, int E) {
  int e = blockIdx.x * blockDim.x + threadIdx.x;
  if (e >= E) return;
  int dst = ei[E + e];
  int slot = offsets[dst] + atomicAdd(&cursor[dst], 1);
  csr_src[slot] = ei[e];
}

// ----------------------------- weight concat [Wl | Wr] -----------------------------
__global__ void k_pack2(const float* __restrict__ Wl, const float* __restrict__ Wr,
                        float* __restrict__ Wcat, int K, int F) {
  int i = blockIdx.x * 256 + threadIdx.x;
  int total = K * 2 * F;
  if (i >= total) return;
  int k = i / (2 * F), j = i - k * 2 * F;
  Wcat[i] = (j < F) ? Wl[k * F + j] : Wr[k * F + (j - F)];
}

// ----------------------------- SGEMM (fp32) 128x64 tile, 8x4/thread -----------------------------
// C[n,M] = A[n,K] @ W[K,M].  Optional fused GAT-score epilogue:
// als[row,h] = sum_c C[row,h*F+c]*a_s[h,c]; ald likewise (F = M/4, heads fully inside a col tile).
__global__ __launch_bounds__(256) void k_sgemm(const float* __restrict__ A,
                                               const float* __restrict__ W,
                                               float* __restrict__ C,
                                               int nrows, int K, int M,
                                               const float* __restrict__ a_s,
                                               const float* __restrict__ a_d,
                                               float* __restrict__ als,
                                               float* __restrict__ ald) {
  __shared__ float As[16][132];
  __shared__ float Ws[16][68];
  const int tid = threadIdx.x;
  const int tx = tid & 15, ty = tid >> 4;
  const int row0 = blockIdx.x * 128, col0 = blockIdx.y * 64;
  float acc[8][4] = {};
  for (int k0 = 0; k0 < K; k0 += 16) {
#pragma unroll
    for (int i = 0; i < 8; i++) {
      int lin = tid + i * 256;
      int kk = lin & 15, r = lin >> 4;
      int row = row0 + r;
      As[kk][r] = (row < nrows) ? A[(size_t)row * K + k0 + kk] : 0.f;
    }
#pragma unroll
    for (int i = 0; i < 4; i++) {
      int lin = tid + i * 256;
      int c = lin & 63, kk = lin >> 6;
      Ws[kk][c] = W[(size_t)(k0 + kk) * M + col0 + c];
    }
    __syncthreads();
#pragma unroll
    for (int kk = 0; kk < 16; kk++) {
      float4 w4 = *(const float4*)&Ws[kk][tx * 4];
      float4 a0 = *(const float4*)&As[kk][ty * 8];
      float4 a1 = *(const float4*)&As[kk][ty * 8 + 4];
      acc[0][0] += a0.x * w4.x; acc[0][1] += a0.x * w4.y; acc[0][2] += a0.x * w4.z; acc[0][3] += a0.x * w4.w;
      acc[1][0] += a0.y * w4.x; acc[1][1] += a0.y * w4.y; acc[1][2] += a0.y * w4.z; acc[1][3] += a0.y * w4.w;
      acc[2][0] += a0.z * w4.x; acc[2][1] += a0.z * w4.y; acc[2][2] += a0.z * w4.z; acc[2][3] += a0.z * w4.w;
      acc[3][0] += a0.w * w4.x; acc[3][1] += a0.w * w4.y; acc[3][2] += a0.w * w4.z; acc[3][3] += a0.w * w4.w;
      acc[4][0] += a1.x * w4.x; acc[4][1] += a1.x * w4.y; acc[4][2] += a1.x * w4.z; acc[4][3] += a1.x * w4.w;
      acc[5][0] += a1.y * w4.x; acc[5][1] += a1.y * w4.y; acc[5][2] += a1.y * w4.z; acc[5][3] += a1.y * w4.w;
      acc[6][0] += a1.z * w4.x; acc[6][1] += a1.z * w4.y; acc[6][2] += a1.z * w4.z; acc[6][3] += a1.z * w4.w;
      acc[7][0] += a1.w * w4.x; acc[7][1] += a1.w * w4.y; acc[7][2] += a1.w * w4.z; acc[7][3] += a1.w * w4.w;
    }
    __syncthreads();
  }
#pragma unroll
  for (int i = 0; i < 8; i++) {
    int row = row0 + ty * 8 + i;
    if (row < nrows)
      *(float4*)&C[(size_t)row * M + col0 + tx * 4] = make_float4(acc[i][0], acc[i][1], acc[i][2], acc[i][3]);
  }
  if (a_s) {
    int F = M >> 2;                  // per-head channels (64 or 32)
    int lphl = F >> 2;               // tx lanes per head (16 or 8)
    int gcol = col0 + tx * 4;
    int h = gcol / F;
    int cc = gcol - h * F;
    float4 s4 = *(const float4*)&a_s[h * F + cc];
    float4 d4 = *(const float4*)&a_d[h * F + cc];
#pragma unroll
    for (int i = 0; i < 8; i++) {
      float ps = acc[i][0] * s4.x + acc[i][1] * s4.y + acc[i][2] * s4.z + acc[i][3] * s4.w;
      float pd = acc[i][0] * d4.x + acc[i][1] * d4.y + acc[i][2] * d4.z + acc[i][3] * d4.w;
      for (int mm = 1; mm < lphl; mm <<= 1) { ps += __shfl_xor(ps, mm); pd += __shfl_xor(pd, mm); }
      if ((tx & (lphl - 1)) == 0) {
        int row = row0 + ty * 8 + i;
        if (row < nrows) { als[row * 4 + h] = ps; ald[row * 4 + h] = pd; }
      }
    }
  }
}

// ----------------------------- SAGE aggregate -----------------------------
// hcat = [hl | hr] with row stride 2F. out[v] = relu(mean hl[src] + bias + hr[v]).
__global__ __launch_bounds__(256) void k_sage_agg(const float* __restrict__ hcat,
                                                  const float* __restrict__ bias,
                                                  const int* __restrict__ offsets,
                                                  const int* __restrict__ csr_src,
                                                  float* __restrict__ out, int n, int F) {
  int wave = threadIdx.x >> 6, lane = threadIdx.x & 63;
  int v = blockIdx.x * 4 + wave;
  if (v >= n || lane >= F) return;
  const int st = 2 * F;
  int d0 = offsets[v], d1 = offsets[v + 1];
  float acc = 0.f;
  int e = d0;
  for (; e + 4 <= d1; e += 4) {
    int s0 = csr_src[e], s1 = csr_src[e + 1], s2 = csr_src[e + 2], s3 = csr_src[e + 3];
    float v0 = hcat[(size_t)s0 * st + lane];
    float v1 = hcat[(size_t)s1 * st + lane];
    float v2 = hcat[(size_t)s2 * st + lane];
    float v3 = hcat[(size_t)s3 * st + lane];
    acc += (v0 + v1) + (v2 + v3);
  }
  for (; e < d1; ++e) acc += hcat[(size_t)csr_src[e] * st + lane];
  int d = d1 - d0;
  float inv = 1.f / (float)(d > 1 ? d : 1);
  float y = acc * inv + bias[lane] + hcat[(size_t)v * st + F + lane];
  out[(size_t)v * F + lane] = fmaxf(y, 0.f);
}

// ----------------------------- GAT softmax stats (online max+sum), 1 pass -----------------------------
__global__ __launch_bounds__(256) void k_gat_stats(const float* __restrict__ als,
                                                   const float* __restrict__ ald,
                                                   const int* __restrict__ offsets,
                                                   const int* __restrict__ csr_src,
                                                   float* __restrict__ mbuf,
                                                   float* __restrict__ isbuf, int n) {
  int wave = threadIdx.x >> 6, lane = threadIdx.x & 63;
  int v = blockIdx.x * 4 + wave;
  if (v >= n) return;
  int d0 = offsets[v], d1 = offsets[v + 1];
  float4 ad4 = *(const float4*)&ald[v * 4];
  float m0 = -1e30f, m1 = -1e30f, m2 = -1e30f, m3 = -1e30f;
  float s0 = 0.f, s1 = 0.f, s2 = 0.f, s3 = 0.f;
  for (int e = d0 + lane; e < d1; e += 64) {
    int s = csr_src[e];
    float4 as4 = *(const float4*)&als[(size_t)s * 4];
    float t0 = as4.x + ad4.x; t0 = t0 > 0.f ? t0 : 0.2f * t0;
    float t1 = as4.y + ad4.y; t1 = t1 > 0.f ? t1 : 0.2f * t1;
    float t2 = as4.z + ad4.z; t2 = t2 > 0.f ? t2 : 0.2f * t2;
    float t3 = as4.w + ad4.w; t3 = t3 > 0.f ? t3 : 0.2f * t3;
    float n0 = fmaxf(m0, t0); s0 = s0 * __expf(m0 - n0) + __expf(t0 - n0); m0 = n0;
    float n1 = fmaxf(m1, t1); s1 = s1 * __expf(m1 - n1) + __expf(t1 - n1); m1 = n1;
    float n2 = fmaxf(m2, t2); s2 = s2 * __expf(m2 - n2) + __expf(t2 - n2); m2 = n2;
    float n3 = fmaxf(m3, t3); s3 = s3 * __expf(m3 - n3) + __expf(t3 - n3); m3 = n3;
  }
  for (int mm = 1; mm < 64; mm <<= 1) {
    float o, os, nm;
    o = __shfl_xor(m0, mm); os = __shfl_xor(s0, mm); nm = fmaxf(m0, o);
    s0 = s0 * __expf(m0 - nm) + os * __expf(o - nm); m0 = nm;
    o = __shfl_xor(m1, mm); os = __shfl_xor(s1, mm); nm = fmaxf(m1, o);
    s1 = s1 * __expf(m1 - nm) + os * __expf(o - nm); m1 = nm;
    o = __shfl_xor(m2, mm); os = __shfl_xor(s2, mm); nm = fmaxf(m2, o);
    s2 = s2 * __expf(m2 - nm) + os * __expf(o - nm); m2 = nm;
    o = __shfl_xor(m3, mm); os = __shfl_xor(s3, mm); nm = fmaxf(m3, o);
    s3 = s3 * __expf(m3 - nm) + os * __expf(o - nm); m3 = nm;
  }
  if (lane == 0) {
    *(float4*)&mbuf[v * 4] = make_float4(m0, m1, m2, m3);
    *(float4*)&isbuf[v * 4] = make_float4(1.f / (s0 + 1e-16f), 1.f / (s1 + 1e-16f),
                                          1.f / (s2 + 1e-16f), 1.f / (s3 + 1e-16f));
  }
}

// ----------------------------- GAT aggregate (alpha inline) + bias + relu + head-mean ----------------
__global__ __launch_bounds__(256) void k_gat_agg(const float* __restrict__ xh,
                                                 const float* __restrict__ als,
                                                 const float* __restrict__ ald,
                                                 const float* __restrict__ mbuf,
                                                 const float* __restrict__ isbuf,
                                                 const float* __restrict__ bias,
                                                 const int* __restrict__ offsets,
                                                 const int* __restrict__ csr_src,
                                                 float* __restrict__ out, int n, int F) {
  int wave = threadIdx.x >> 6, lane = threadIdx.x & 63;
  int v = blockIdx.x * 4 + wave;
  if (v >= n || lane >= F) return;
  int lph = F >> 2;
  int h = lane / lph;
  int c0 = lane * 4;
  const int st = 4 * F;
  float ad = ald[v * 4 + h];
  float mh = mbuf[v * 4 + h];
  float ish = isbuf[v * 4 + h];
  int d0 = offsets[v], d1 = offsets[v + 1];
  float a0 = 0.f, a1 = 0.f, a2 = 0.f, a3 = 0.f;
  int e = d0;
  for (; e + 4 <= d1; e += 4) {
    int s0 = csr_src[e], s1 = csr_src[e + 1], s2 = csr_src[e + 2], s3 = csr_src[e + 3];
    float l0 = als[(size_t)s0 * 4 + h];
    float l1 = als[(size_t)s1 * 4 + h];
    float l2 = als[(size_t)s2 * 4 + h];
    float l3 = als[(size_t)s3 * 4 + h];
    float4 x0 = *(const float4*)&xh[(size_t)s0 * st + c0];
    float4 x1 = *(const float4*)&xh[(size_t)s1 * st + c0];
    float4 x2 = *(const float4*)&xh[(size_t)s2 * st + c0];
    float4 x3 = *(const float4*)&xh[(size_t)s3 * st + c0];
    float t0 = l0 + ad; t0 = t0 > 0.f ? t0 : 0.2f * t0; float w0 = __expf(t0 - mh) * ish;
    float t1 = l1 + ad; t1 = t1 > 0.f ? t1 : 0.2f * t1; float w1 = __expf(t1 - mh) * ish;
    float t2 = l2 + ad; t2 = t2 > 0.f ? t2 : 0.2f * t2; float w2 = __expf(t2 - mh) * ish;
    float t3 = l3 + ad; t3 = t3 > 0.f ? t3 : 0.2f * t3; float w3 = __expf(t3 - mh) * ish;
    a0 += w0 * x0.x + w1 * x1.x + w2 * x2.x + w3 * x3.x;
    a1 += w0 * x0.y + w1 * x1.y + w2 * x2.y + w3 * x3.y;
    a2 += w0 * x0.z + w1 * x1.z + w2 * x2.z + w3 * x3.z;
    a3 += w0 * x0.w + w1 * x1.w + w2 * x2.w + w3 * x3.w;
  }
  for (; e < d1; ++e) {
    int s = csr_src[e];
    float l = als[(size_t)s * 4 + h];
    float4 x4 = *(const float4*)&xh[(size_t)s * st + c0];
    float t = l + ad; t = t > 0.f ? t : 0.2f * t;
    float w = __expf(t - mh) * ish;
    a0 += w * x4.x; a1 += w * x4.y; a2 += w * x4.z; a3 += w * x4.w;
  }
  float4 b4 = *(const float4*)&bias[c0];
  a0 = fmaxf(a0 + b4.x, 0.f);
  a1 = fmaxf(a1 + b4.y, 0.f);
  a2 = fmaxf(a2 + b4.z, 0.f);
  a3 = fmaxf(a3 + b4.w, 0.f);
  for (int mm = lph; mm < F; mm <<= 1) {
    a0 += __shfl_xor(a0, mm);
    a1 += __shfl_xor(a1, mm);
    a2 += __shfl_xor(a2, mm);
    a3 += __shfl_xor(a3, mm);
  }
  if (lane < lph) {
    float4 o = make_float4(a0 * 0.25f, a1 * 0.25f, a2 * 0.25f, a3 * 0.25f);
    *(float4*)&out[(size_t)v * F + c0] = o;
  }
}

// ----------------------------- penalty + exp scale + L2 normalize -----------------------------
__global__ __launch_bounds__(256) void k_final(const float* __restrict__ y,
                                               const float* __restrict__ Wp,
                                               const float* __restrict__ bp,
                                               float* __restrict__ out, int n) {
  int wave = threadIdx.x >> 6, lane = threadIdx.x & 63;
  int v = blockIdx.x * 4 + wave;
  if (v >= n || lane >= 32) return;
  float yv = y[(size_t)v * 32 + lane];
  float p = yv * Wp[lane];
  for (int m = 1; m < 32; m <<= 1) p += __shfl_xor(p, m);
  p += bp[0];
  float s = __expf(p);
  float xv = yv * s;
  float q = xv * xv;
  for (int m = 1; m < 32; m <<= 1) q += __shfl_xor(q, m);
  float nrm = sqrtf(q);
  nrm = fmaxf(nrm, 1e-12f);
  out[(size_t)v * 32 + lane] = xv / nrm;
}

// ----------------------------- launch -----------------------------
extern "C" void kernel_launch(void* const* d_in, const int* in_sizes, int n_in,
                              void* d_out, int out_size, void* d_ws, size_t ws_size,
                              hipStream_t stream) {
  (void)in_sizes; (void)n_in; (void)out_size; (void)ws_size;
  const float* x   = (const float*)d_in[0];
  const int*   ei  = (const int*)d_in[1];
  const float* W1l = (const float*)d_in[2];
  const float* b1l = (const float*)d_in[3];
  const float* W1r = (const float*)d_in[4];
  const float* Wa1 = (const float*)d_in[5];
  const float* as1 = (const float*)d_in[6];
  const float* ad1 = (const float*)d_in[7];
  const float* ba1 = (const float*)d_in[8];
  const float* W2l = (const float*)d_in[9];
  const float* b2l = (const float*)d_in[10];
  const float* W2r = (const float*)d_in[11];
  const float* Wa2 = (const float*)d_in[12];
  const float* as2 = (const float*)d_in[13];
  const float* ad2 = (const float*)d_in[14];
  const float* ba2 = (const float*)d_in[15];
  const float* W3l = (const float*)d_in[16];
  const float* b3l = (const float*)d_in[17];
  const float* W3r = (const float*)d_in[18];
  const float* Wa3 = (const float*)d_in[19];
  const float* as3 = (const float*)d_in[20];
  const float* ad3 = (const float*)d_in[21];
  const float* ba3 = (const float*)d_in[22];
  const float* Wp  = (const float*)d_in[23];
  const float* bp  = (const float*)d_in[24];
  float* out = (float*)d_out;

  char* ws = (char*)d_ws;
  size_t off = 0;
  auto alloc = [&](size_t bytes) -> void* {
    void* p = ws + off;
    off += (bytes + 255) & ~(size_t)255;
    return p;
  };
  int* deg    = (int*)alloc((size_t)NNODES * 4);
  int* offs   = (int*)alloc((size_t)(NNODES + 1) * 4);
  int* cursor = (int*)alloc((size_t)NNODES * 4);
  int* csr    = (int*)alloc((size_t)NEDGES * 4);
  float* Wc1  = (float*)alloc((size_t)128 * 128 * 4);
  float* Wc2  = (float*)alloc((size_t)64 * 128 * 4);
  float* Wc3  = (float*)alloc((size_t)64 * 64 * 4);
  float* bufA = (float*)alloc((size_t)NNODES * 256 * 4);  // xh
  float* bufCD= (float*)alloc((size_t)NNODES * 128 * 4);  // [hl|hr]
  float* bufB = (float*)alloc((size_t)NNODES * 64 * 4);   // layer io
  float* als  = (float*)alloc((size_t)NNODES * 4 * 4);
  float* ald  = (float*)alloc((size_t)NNODES * 4 * 4);
  float* mbuf = (float*)alloc((size_t)NNODES * 4 * 4);
  float* isbuf= (float*)alloc((size_t)NNODES * 4 * 4);

  hipMemsetAsync(deg, 0, (size_t)NNODES * 4, stream);
  hipMemsetAsync(cursor, 0, (size_t)NNODES * 4, stream);
  int eb = (NEDGES + 255) / 256;
  k_hist<<<eb, 256, 0, stream>>>(ei, deg, NEDGES);
  k_pack2<<<(128 * 128 + 255) / 256, 256, 0, stream>>>(W1l, W1r, Wc1, 128, 64);
  k_pack2<<<(64 * 128 + 255) / 256, 256, 0, stream>>>(W2l, W2r, Wc2, 64, 64);
  k_pack2<<<(64 * 64 + 255) / 256, 256, 0, stream>>>(W3l, W3r, Wc3, 64, 32);
  k_scan<<<1, 1024, 0, stream>>>(deg, offs, NNODES);
  k_fill<<<eb, 256, 0, stream>>>(ei, offs, cursor, csr, NEDGES);

  int nb = (NNODES + 3) / 4;
  auto gemm = [&](const float* A, const float* W, float* C, int K, int M,
                  const float* asp, const float* adp) {
    dim3 grid((NNODES + 127) / 128, M / 64);
    k_sgemm<<<grid, 256, 0, stream>>>(A, W, C, NNODES, K, M, asp, adp, als, ald);
  };

  // ---- block 1 (in=128, F=64) ----
  gemm(x, Wc1, bufCD, 128, 128, nullptr, nullptr);
  k_sage_agg<<<nb, 256, 0, stream>>>(bufCD, b1l, offs, csr, bufB, NNODES, 64);
  gemm(bufB, Wa1, bufA, 64, 256, as1, ad1);
  k_gat_stats<<<nb, 256, 0, stream>>>(als, ald, offs, csr, mbuf, isbuf, NNODES);
  k_gat_agg<<<nb, 256, 0, stream>>>(bufA, als, ald, mbuf, isbuf, ba1, offs, csr, bufB, NNODES, 64);

  // ---- block 2 (in=64, F=64) ----
  gemm(bufB, Wc2, bufCD, 64, 128, nullptr, nullptr);
  k_sage_agg<<<nb, 256, 0, stream>>>(bufCD, b2l, offs, csr, bufB, NNODES, 64);
  gemm(bufB, Wa2, bufA, 64, 256, as2, ad2);
  k_gat_stats<<<nb, 256, 0, stream>>>(als, ald, offs, csr, mbuf, isbuf, NNODES);
  k_gat_agg<<<nb, 256, 0, stream>>>(bufA, als, ald, mbuf, isbuf, ba2, offs, csr, bufB, NNODES, 64);

  // ---- block 3 (in=64, F=32) ----
  gemm(bufB, Wc3, bufCD, 64, 64, nullptr, nullptr);
  k_sage_agg<<<nb, 256, 0, stream>>>(bufCD, b3l, offs, csr, bufB, NNODES, 32);
  gemm(bufB, Wa3, bufA, 32, 128, as3, ad3);
  k_gat_stats<<<nb, 256, 0, stream>>>(als, ald, offs, csr, mbuf, isbuf, NNODES);
  k_gat_agg<<<nb, 256, 0, stream>>>(bufA, als, ald, mbuf, isbuf, ba3, offs, csr, bufB, NNODES, 32);

  k_final<<<nb, 256, 0, stream>>>(bufB, Wp, bp, out, NNODES);
}

// Round 3
// 1252.624 us; speedup vs baseline: 1.5496x; 1.3347x over previous
//
#include <hip/hip_runtime.h>
#include <math.h>

#define NNODES 100000
#define NEDGES 1600000

typedef unsigned short bfu;

__device__ __forceinline__ float b2f(bfu u) {
  union { unsigned u; float f; } v; v.u = ((unsigned)u) << 16;
  return v.f;
}
__device__ __forceinline__ bfu f2b(float f) {
  union { float f; unsigned u; } v; v.f = f;
  unsigned r = v.u + 0x7fffu + ((v.u >> 16) & 1u);
  return (bfu)(r >> 16);
}

// ----------------------------- CSR build -----------------------------
__global__ void k_hist(const int* __restrict__ ei, int* __restrict__ deg, int E) {
  int e = blockIdx.x * blockDim.x + threadIdx.x;
  if (e < E) atomicAdd(&deg[ei[E + e]], 1);
}

__global__ __launch_bounds__(1024) void k_scan(const int* __restrict__ deg,
                                               int* __restrict__ offsets, int n) {
  __shared__ int sums[1024];
  int t = threadIdx.x;
  int chunk = (n + 1023) / 1024;
  int start = t * chunk;
  int end = min(start + chunk, n);
  int local = 0;
  for (int i = start; i < end; i++) local += deg[i];
  sums[t] = local;
  __syncthreads();
  for (int off = 1; off < 1024; off <<= 1) {
    int v = (t >= off) ? sums[t - off] : 0;
    __syncthreads();
    sums[t] += v;
    __syncthreads();
  }
  int run = sums[t] - local;  // exclusive prefix
  for (int i = start; i < end; i++) { offsets[i] = run; run += deg[i]; }
  if (t == 1023) offsets[n] = sums[1023];
}

__global__ void k_fill(const int* __restrict__ ei, const int* __restrict__ offsets,
                       int* __restrict__ cursor, int* __restrict__ csr_src, int E) {
  int e = blockIdx.x * blockDim.x + threadIdx.x;
  if (e >= E) return;
  int dst = ei[E + e];
  int slot = offsets[dst] + atomicAdd(&cursor[dst], 1);
  csr_src[slot] = ei[e];
}

// ----------------------------- weight concat [Wl | Wr] -----------------------------
__global__ void k_pack2(const float* __restrict__ Wl, const float* __restrict__ Wr,
                        float* __restrict__ Wcat, int K, int F) {
  int i = blockIdx.x * 256 + threadIdx.x;
  int total = K * 2 * F;
  if (i >= total) return;
  int k = i / (2 * F), j = i - k * 2 * F;
  Wcat[i] = (j < F) ? Wl[k * F + j] : Wr[k * F + (j - F)];
}

// ----------------------------- SGEMM (fp32 math) 128x64 tile, 8x4/thread ----------------------
// C[n,M] = A[n,K] @ W[K,M]. Writes bf16 (Cb). Optional fused GAT-score epilogue (fp32-exact):
// als[row,h] = sum_c C[row,h*F+c]*a_s[h,c]; ald likewise.
__global__ __launch_bounds__(256) void k_sgemm(const float* __restrict__ A,
                                               const float* __restrict__ W,
                                               bfu* __restrict__ Cb,
                                               int nrows, int K, int M,
                                               const float* __restrict__ a_s,
                                               const float* __restrict__ a_d,
                                               float* __restrict__ als,
                                               float* __restrict__ ald) {
  __shared__ float As[16][132];
  __shared__ float Ws[16][68];
  const int tid = threadIdx.x;
  const int tx = tid & 15, ty = tid >> 4;
  const int row0 = blockIdx.x * 128, col0 = blockIdx.y * 64;
  float acc[8][4] = {};
  for (int k0 = 0; k0 < K; k0 += 16) {
#pragma unroll
    for (int i = 0; i < 8; i++) {
      int lin = tid + i * 256;
      int kk = lin & 15, r = lin >> 4;
      int row = row0 + r;
      As[kk][r] = (row < nrows) ? A[(size_t)row * K + k0 + kk] : 0.f;
    }
#pragma unroll
    for (int i = 0; i < 4; i++) {
      int lin = tid + i * 256;
      int c = lin & 63, kk = lin >> 6;
      Ws[kk][c] = W[(size_t)(k0 + kk) * M + col0 + c];
    }
    __syncthreads();
#pragma unroll
    for (int kk = 0; kk < 16; kk++) {
      float4 w4 = *(const float4*)&Ws[kk][tx * 4];
      float4 a0 = *(const float4*)&As[kk][ty * 8];
      float4 a1 = *(const float4*)&As[kk][ty * 8 + 4];
      acc[0][0] += a0.x * w4.x; acc[0][1] += a0.x * w4.y; acc[0][2] += a0.x * w4.z; acc[0][3] += a0.x * w4.w;
      acc[1][0] += a0.y * w4.x; acc[1][1] += a0.y * w4.y; acc[1][2] += a0.y * w4.z; acc[1][3] += a0.y * w4.w;
      acc[2][0] += a0.z * w4.x; acc[2][1] += a0.z * w4.y; acc[2][2] += a0.z * w4.z; acc[2][3] += a0.z * w4.w;
      acc[3][0] += a0.w * w4.x; acc[3][1] += a0.w * w4.y; acc[3][2] += a0.w * w4.z; acc[3][3] += a0.w * w4.w;
      acc[4][0] += a1.x * w4.x; acc[4][1] += a1.x * w4.y; acc[4][2] += a1.x * w4.z; acc[4][3] += a1.x * w4.w;
      acc[5][0] += a1.y * w4.x; acc[5][1] += a1.y * w4.y; acc[5][2] += a1.y * w4.z; acc[5][3] += a1.y * w4.w;
      acc[6][0] += a1.z * w4.x; acc[6][1] += a1.z * w4.y; acc[6][2] += a1.z * w4.z; acc[6][3] += a1.z * w4.w;
      acc[7][0] += a1.w * w4.x; acc[7][1] += a1.w * w4.y; acc[7][2] += a1.w * w4.z; acc[7][3] += a1.w * w4.w;
    }
    __syncthreads();
  }
#pragma unroll
  for (int i = 0; i < 8; i++) {
    int row = row0 + ty * 8 + i;
    if (row < nrows) {
      ushort4 o;
      o.x = f2b(acc[i][0]); o.y = f2b(acc[i][1]); o.z = f2b(acc[i][2]); o.w = f2b(acc[i][3]);
      *(ushort4*)&Cb[(size_t)row * M + col0 + tx * 4] = o;
    }
  }
  if (a_s) {
    int F = M >> 2;                  // per-head channels (64 or 32)
    int lphl = F >> 2;               // tx lanes per head (16 or 8)
    int gcol = col0 + tx * 4;
    int h = gcol / F;
    int cc = gcol - h * F;
    float4 s4 = *(const float4*)&a_s[h * F + cc];
    float4 d4 = *(const float4*)&a_d[h * F + cc];
#pragma unroll
    for (int i = 0; i < 8; i++) {
      float ps = acc[i][0] * s4.x + acc[i][1] * s4.y + acc[i][2] * s4.z + acc[i][3] * s4.w;
      float pd = acc[i][0] * d4.x + acc[i][1] * d4.y + acc[i][2] * d4.z + acc[i][3] * d4.w;
      for (int mm = 1; mm < lphl; mm <<= 1) { ps += __shfl_xor(ps, mm); pd += __shfl_xor(pd, mm); }
      if ((tx & (lphl - 1)) == 0) {
        int row = row0 + ty * 8 + i;
        if (row < nrows) { als[row * 4 + h] = ps; ald[row * 4 + h] = pd; }
      }
    }
  }
}

// ----------------------------- SAGE aggregate (bf16 gather, fp32 accum) -----------------------
// hcat = [hl | hr] bf16 with row stride 2F. out[v] = relu(mean hl[src] + bias + hr[v]).
__global__ __launch_bounds__(256) void k_sage_agg(const bfu* __restrict__ hcat,
                                                  const float* __restrict__ bias,
                                                  const int* __restrict__ offsets,
                                                  const int* __restrict__ csr_src,
                                                  float* __restrict__ out, int n, int F) {
  int wave = threadIdx.x >> 6, lane = threadIdx.x & 63;
  int v = blockIdx.x * 4 + wave;
  if (v >= n || lane >= F) return;
  const int st = 2 * F;
  int d0 = offsets[v], d1 = offsets[v + 1];
  float acc = 0.f;
  int e = d0;
  for (; e + 4 <= d1; e += 4) {
    int s0 = csr_src[e], s1 = csr_src[e + 1], s2 = csr_src[e + 2], s3 = csr_src[e + 3];
    float v0 = b2f(hcat[(size_t)s0 * st + lane]);
    float v1 = b2f(hcat[(size_t)s1 * st + lane]);
    float v2 = b2f(hcat[(size_t)s2 * st + lane]);
    float v3 = b2f(hcat[(size_t)s3 * st + lane]);
    acc += (v0 + v1) + (v2 + v3);
  }
  for (; e < d1; ++e) acc += b2f(hcat[(size_t)csr_src[e] * st + lane]);
  int d = d1 - d0;
  float inv = 1.f / (float)(d > 1 ? d : 1);
  float y = acc * inv + bias[lane] + b2f(hcat[(size_t)v * st + F + lane]);
  out[(size_t)v * F + lane] = fmaxf(y, 0.f);
}

// ------------- GAT aggregate: online softmax + weighted sum + bias + relu + head-mean ---------
__global__ __launch_bounds__(256) void k_gat_agg(const bfu* __restrict__ xh,
                                                 const float* __restrict__ als,
                                                 const float* __restrict__ ald,
                                                 const float* __restrict__ bias,
                                                 const int* __restrict__ offsets,
                                                 const int* __restrict__ csr_src,
                                                 float* __restrict__ out, int n, int F) {
  int wave = threadIdx.x >> 6, lane = threadIdx.x & 63;
  int v = blockIdx.x * 4 + wave;
  if (v >= n || lane >= F) return;
  int lph = F >> 2;
  int h = lane / lph;
  int c0 = lane * 4;
  const int st = 4 * F;
  float ad = ald[v * 4 + h];
  int d0 = offsets[v], d1 = offsets[v + 1];
  float m = -1e30f, sum = 0.f;
  float a0 = 0.f, a1 = 0.f, a2 = 0.f, a3 = 0.f;

  auto step = [&](int s, float l, ushort4 xu) {
    float t = l + ad; t = t > 0.f ? t : 0.2f * t;
    float nM = fmaxf(m, t);
    if (nM > m) {
      float r = __expf(m - nM);
      sum *= r; a0 *= r; a1 *= r; a2 *= r; a3 *= r;
      m = nM;
    }
    float p = __expf(t - m);
    sum += p;
    a0 += p * b2f(xu.x); a1 += p * b2f(xu.y); a2 += p * b2f(xu.z); a3 += p * b2f(xu.w);
  };

  int e = d0;
  for (; e + 4 <= d1; e += 4) {
    int s0 = csr_src[e], s1 = csr_src[e + 1], s2 = csr_src[e + 2], s3 = csr_src[e + 3];
    float l0 = als[(size_t)s0 * 4 + h];
    float l1 = als[(size_t)s1 * 4 + h];
    float l2 = als[(size_t)s2 * 4 + h];
    float l3 = als[(size_t)s3 * 4 + h];
    ushort4 x0 = *(const ushort4*)&xh[(size_t)s0 * st + c0];
    ushort4 x1 = *(const ushort4*)&xh[(size_t)s1 * st + c0];
    ushort4 x2 = *(const ushort4*)&xh[(size_t)s2 * st + c0];
    ushort4 x3 = *(const ushort4*)&xh[(size_t)s3 * st + c0];
    step(s0, l0, x0); step(s1, l1, x1); step(s2, l2, x2); step(s3, l3, x3);
  }
  for (; e < d1; ++e) {
    int s = csr_src[e];
    float l = als[(size_t)s * 4 + h];
    ushort4 xu = *(const ushort4*)&xh[(size_t)s * st + c0];
    step(s, l, xu);
  }

  float inv = 1.f / (sum + 1e-16f);
  a0 *= inv; a1 *= inv; a2 *= inv; a3 *= inv;
  float4 b4 = *(const float4*)&bias[c0];
  a0 = fmaxf(a0 + b4.x, 0.f);
  a1 = fmaxf(a1 + b4.y, 0.f);
  a2 = fmaxf(a2 + b4.z, 0.f);
  a3 = fmaxf(a3 + b4.w, 0.f);
  for (int mm = lph; mm < F; mm <<= 1) {
    a0 += __shfl_xor(a0, mm);
    a1 += __shfl_xor(a1, mm);
    a2 += __shfl_xor(a2, mm);
    a3 += __shfl_xor(a3, mm);
  }
  if (lane < lph) {
    float4 o = make_float4(a0 * 0.25f, a1 * 0.25f, a2 * 0.25f, a3 * 0.25f);
    *(float4*)&out[(size_t)v * F + c0] = o;
  }
}

// ----------------------------- penalty + exp scale + L2 normalize -----------------------------
__global__ __launch_bounds__(256) void k_final(const float* __restrict__ y,
                                               const float* __restrict__ Wp,
                                               const float* __restrict__ bp,
                                               float* __restrict__ out, int n) {
  int wave = threadIdx.x >> 6, lane = threadIdx.x & 63;
  int v = blockIdx.x * 4 + wave;
  if (v >= n || lane >= 32) return;
  float yv = y[(size_t)v * 32 + lane];
  float p = yv * Wp[lane];
  for (int m = 1; m < 32; m <<= 1) p += __shfl_xor(p, m);
  p += bp[0];
  float s = __expf(p);
  float xv = yv * s;
  float q = xv * xv;
  for (int m = 1; m < 32; m <<= 1) q += __shfl_xor(q, m);
  float nrm = sqrtf(q);
  nrm = fmaxf(nrm, 1e-12f);
  out[(size_t)v * 32 + lane] = xv / nrm;
}

// ----------------------------- launch -----------------------------
extern "C" void kernel_launch(void* const* d_in, const int* in_sizes, int n_in,
                              void* d_out, int out_size, void* d_ws, size_t ws_size,
                              hipStream_t stream) {
  (void)in_sizes; (void)n_in; (void)out_size; (void)ws_size;
  const float* x   = (const float*)d_in[0];
  const int*   ei  = (const int*)d_in[1];
  const float* W1l = (const float*)d_in[2];
  const float* b1l = (const float*)d_in[3];
  const float* W1r = (const float*)d_in[4];
  const float* Wa1 = (const float*)d_in[5];
  const float* as1 = (const float*)d_in[6];
  const float* ad1 = (const float*)d_in[7];
  const float* ba1 = (const float*)d_in[8];
  const float* W2l = (const float*)d_in[9];
  const float* b2l = (const float*)d_in[10];
  const float* W2r = (const float*)d_in[11];
  const float* Wa2 = (const float*)d_in[12];
  const float* as2 = (const float*)d_in[13];
  const float* ad2 = (const float*)d_in[14];
  const float* ba2 = (const float*)d_in[15];
  const float* W3l = (const float*)d_in[16];
  const float* b3l = (const float*)d_in[17];
  const float* W3r = (const float*)d_in[18];
  const float* Wa3 = (const float*)d_in[19];
  const float* as3 = (const float*)d_in[20];
  const float* ad3 = (const float*)d_in[21];
  const float* ba3 = (const float*)d_in[22];
  const float* Wp  = (const float*)d_in[23];
  const float* bp  = (const float*)d_in[24];
  float* out = (float*)d_out;

  char* ws = (char*)d_ws;
  size_t off = 0;
  auto alloc = [&](size_t bytes) -> void* {
    void* p = ws + off;
    off += (bytes + 255) & ~(size_t)255;
    return p;
  };
  int* deg    = (int*)alloc((size_t)NNODES * 4);
  int* offs   = (int*)alloc((size_t)(NNODES + 1) * 4);
  int* cursor = (int*)alloc((size_t)NNODES * 4);
  int* csr    = (int*)alloc((size_t)NEDGES * 4);
  float* Wc1  = (float*)alloc((size_t)128 * 128 * 4);
  float* Wc2  = (float*)alloc((size_t)64 * 128 * 4);
  float* Wc3  = (float*)alloc((size_t)64 * 64 * 4);
  bfu* bufA   = (bfu*)alloc((size_t)NNODES * 256 * 2);   // xh (bf16)
  bfu* bufCD  = (bfu*)alloc((size_t)NNODES * 128 * 2);   // [hl|hr] (bf16)
  float* bufB = (float*)alloc((size_t)NNODES * 64 * 4);  // layer io (fp32)
  float* als  = (float*)alloc((size_t)NNODES * 4 * 4);
  float* ald  = (float*)alloc((size_t)NNODES * 4 * 4);

  hipMemsetAsync(deg, 0, (size_t)NNODES * 4, stream);
  hipMemsetAsync(cursor, 0, (size_t)NNODES * 4, stream);
  int eb = (NEDGES + 255) / 256;
  k_hist<<<eb, 256, 0, stream>>>(ei, deg, NEDGES);
  k_pack2<<<(128 * 128 + 255) / 256, 256, 0, stream>>>(W1l, W1r, Wc1, 128, 64);
  k_pack2<<<(64 * 128 + 255) / 256, 256, 0, stream>>>(W2l, W2r, Wc2, 64, 64);
  k_pack2<<<(64 * 64 + 255) / 256, 256, 0, stream>>>(W3l, W3r, Wc3, 64, 32);
  k_scan<<<1, 1024, 0, stream>>>(deg, offs, NNODES);
  k_fill<<<eb, 256, 0, stream>>>(ei, offs, cursor, csr, NEDGES);

  int nb = (NNODES + 3) / 4;
  auto gemm = [&](const float* A, const float* W, bfu* C, int K, int M,
                  const float* asp, const float* adp) {
    dim3 grid((NNODES + 127) / 128, M / 64);
    k_sgemm<<<grid, 256, 0, stream>>>(A, W, C, NNODES, K, M, asp, adp, als, ald);
  };

  // ---- block 1 (in=128, F=64) ----
  gemm(x, Wc1, bufCD, 128, 128, nullptr, nullptr);
  k_sage_agg<<<nb, 256, 0, stream>>>(bufCD, b1l, offs, csr, bufB, NNODES, 64);
  gemm(bufB, Wa1, bufA, 64, 256, as1, ad1);
  k_gat_agg<<<nb, 256, 0, stream>>>(bufA, als, ald, ba1, offs, csr, bufB, NNODES, 64);

  // ---- block 2 (in=64, F=64) ----
  gemm(bufB, Wc2, bufCD, 64, 128, nullptr, nullptr);
  k_sage_agg<<<nb, 256, 0, stream>>>(bufCD, b2l, offs, csr, bufB, NNODES, 64);
  gemm(bufB, Wa2, bufA, 64, 256, as2, ad2);
  k_gat_agg<<<nb, 256, 0, stream>>>(bufA, als, ald, ba2, offs, csr, bufB, NNODES, 64);

  // ---- block 3 (in=64, F=32) ----
  gemm(bufB, Wc3, bufCD, 64, 64, nullptr, nullptr);
  k_sage_agg<<<nb, 256, 0, stream>>>(bufCD, b3l, offs, csr, bufB, NNODES, 32);
  gemm(bufB, Wa3, bufA, 32, 128, as3, ad3);
  k_gat_agg<<<nb, 256, 0, stream>>>(bufA, als, ald, ba3, offs, csr, bufB, NNODES, 32);

  k_final<<<nb, 256, 0, stream>>>(bufB, Wp, bp, out, NNODES);
}

// Round 4
// 1102.849 us; speedup vs baseline: 1.7601x; 1.1358x over previous
//
#include <hip/hip_runtime.h>
#include <math.h>

#define NNODES 100000
#define NEDGES 1600000
#define SCAN_CHUNK 1024
#define SCAN_BLOCKS ((NNODES + SCAN_CHUNK - 1) / SCAN_CHUNK)

typedef unsigned short bfu;

__device__ __forceinline__ float b2f(bfu u) {
  union { unsigned u; float f; } v; v.u = ((unsigned)u) << 16;
  return v.f;
}
__device__ __forceinline__ bfu f2b(float f) {
  union { float f; unsigned u; } v; v.f = f;
  unsigned r = v.u + 0x7fffu + ((v.u >> 16) & 1u);
  return (bfu)(r >> 16);
}

// ----------------------------- CSR build -----------------------------
__global__ void k_hist(const int* __restrict__ ei, int* __restrict__ deg, int E) {
  int e = blockIdx.x * blockDim.x + threadIdx.x;
  if (e < E) atomicAdd(&deg[ei[E + e]], 1);
}

// phase 1: per-block sums of 1024 degrees
__global__ __launch_bounds__(256) void k_scan1(const int* __restrict__ deg,
                                               int* __restrict__ bsums, int n) {
  __shared__ int red[4];
  int base = blockIdx.x * SCAN_CHUNK + threadIdx.x * 4;
  int s = 0;
#pragma unroll
  for (int j = 0; j < 4; j++) {
    int i = base + j;
    if (i < n) s += deg[i];
  }
  for (int m = 1; m < 64; m <<= 1) s += __shfl_xor(s, m);
  int wave = threadIdx.x >> 6, lane = threadIdx.x & 63;
  if (lane == 0) red[wave] = s;
  __syncthreads();
  if (threadIdx.x == 0) bsums[blockIdx.x] = red[0] + red[1] + red[2] + red[3];
}

// phase 2: exclusive scan of block sums (one small block), writes offsets[n]=total
__global__ __launch_bounds__(128) void k_scan2(int* __restrict__ bsums,
                                               int* __restrict__ offsets, int n) {
  __shared__ int sh[128];
  int t = threadIdx.x;
  int v = (t < SCAN_BLOCKS) ? bsums[t] : 0;
  sh[t] = v;
  __syncthreads();
  for (int off = 1; off < 128; off <<= 1) {
    int u = (t >= off) ? sh[t - off] : 0;
    __syncthreads();
    sh[t] += u;
    __syncthreads();
  }
  if (t < SCAN_BLOCKS) bsums[t] = sh[t] - v;          // exclusive
  if (t == 127) offsets[n] = sh[127];                  // total
}

// phase 3: per-block exclusive scan of degrees + block offset -> offsets[0..n)
__global__ __launch_bounds__(256) void k_scan3(const int* __restrict__ deg,
                                               const int* __restrict__ bsums,
                                               int* __restrict__ offsets, int n) {
  __shared__ int sh[256];
  int t = threadIdx.x;
  int base = blockIdx.x * SCAN_CHUNK + t * 4;
  int d[4];
#pragma unroll
  for (int j = 0; j < 4; j++) d[j] = (base + j < n) ? deg[base + j] : 0;
  int tsum = d[0] + d[1] + d[2] + d[3];
  sh[t] = tsum;
  __syncthreads();
  for (int off = 1; off < 256; off <<= 1) {
    int u = (t >= off) ? sh[t - off] : 0;
    __syncthreads();
    sh[t] += u;
    __syncthreads();
  }
  int run = bsums[blockIdx.x] + sh[t] - tsum;  // exclusive prefix for this thread's 4
#pragma unroll
  for (int j = 0; j < 4; j++) {
    if (base + j < n) offsets[base + j] = run;
    run += d[j];
  }
}

__global__ void k_fill(const int* __restrict__ ei, const int* __restrict__ offsets,
                       int* __restrict__ cursor, int* __restrict__ csr_src, int E) {
  int e = blockIdx.x * blockDim.x + threadIdx.x;
  if (e >= E) return;
  int dst = ei[E + e];
  int slot = offsets[dst] + atomicAdd(&cursor[dst], 1);
  csr_src[slot] = ei[e];
}

// ----------------------------- weight concat [Wl | Wr] -----------------------------
__global__ void k_pack2(const float* __restrict__ Wl, const float* __restrict__ Wr,
                        float* __restrict__ Wcat, int K, int F) {
  int i = blockIdx.x * 256 + threadIdx.x;
  int total = K * 2 * F;
  if (i >= total) return;
  int k = i / (2 * F), j = i - k * 2 * F;
  Wcat[i] = (j < F) ? Wl[k * F + j] : Wr[k * F + (j - F)];
}

// ----------------------------- SGEMM (fp32 math) 128x64 tile, 8x4/thread ----------------------
// C[n,M] = A[n,K] @ W[K,M]. Writes bf16 (Cb). Optional fused GAT-score epilogue (fp32-exact):
// als[row,h] = sum_c C[row,h*F+c]*a_s[h,c]; ald likewise.
__global__ __launch_bounds__(256) void k_sgemm(const float* __restrict__ A,
                                               const float* __restrict__ W,
                                               bfu* __restrict__ Cb,
                                               int nrows, int K, int M,
                                               const float* __restrict__ a_s,
                                               const float* __restrict__ a_d,
                                               float* __restrict__ als,
                                               float* __restrict__ ald) {
  __shared__ float As[16][132];
  __shared__ float Ws[16][68];
  const int tid = threadIdx.x;
  const int tx = tid & 15, ty = tid >> 4;
  const int row0 = blockIdx.x * 128, col0 = blockIdx.y * 64;
  float acc[8][4] = {};
  for (int k0 = 0; k0 < K; k0 += 16) {
#pragma unroll
    for (int i = 0; i < 8; i++) {
      int lin = tid + i * 256;
      int kk = lin & 15, r = lin >> 4;
      int row = row0 + r;
      As[kk][r] = (row < nrows) ? A[(size_t)row * K + k0 + kk] : 0.f;
    }
#pragma unroll
    for (int i = 0; i < 4; i++) {
      int lin = tid + i * 256;
      int c = lin & 63, kk = lin >> 6;
      Ws[kk][c] = W[(size_t)(k0 + kk) * M + col0 + c];
    }
    __syncthreads();
#pragma unroll
    for (int kk = 0; kk < 16; kk++) {
      float4 w4 = *(const float4*)&Ws[kk][tx * 4];
      float4 a0 = *(const float4*)&As[kk][ty * 8];
      float4 a1 = *(const float4*)&As[kk][ty * 8 + 4];
      acc[0][0] += a0.x * w4.x; acc[0][1] += a0.x * w4.y; acc[0][2] += a0.x * w4.z; acc[0][3] += a0.x * w4.w;
      acc[1][0] += a0.y * w4.x; acc[1][1] += a0.y * w4.y; acc[1][2] += a0.y * w4.z; acc[1][3] += a0.y * w4.w;
      acc[2][0] += a0.z * w4.x; acc[2][1] += a0.z * w4.y; acc[2][2] += a0.z * w4.z; acc[2][3] += a0.z * w4.w;
      acc[3][0] += a0.w * w4.x; acc[3][1] += a0.w * w4.y; acc[3][2] += a0.w * w4.z; acc[3][3] += a0.w * w4.w;
      acc[4][0] += a1.x * w4.x; acc[4][1] += a1.x * w4.y; acc[4][2] += a1.x * w4.z; acc[4][3] += a1.x * w4.w;
      acc[5][0] += a1.y * w4.x; acc[5][1] += a1.y * w4.y; acc[5][2] += a1.y * w4.z; acc[5][3] += a1.y * w4.w;
      acc[6][0] += a1.z * w4.x; acc[6][1] += a1.z * w4.y; acc[6][2] += a1.z * w4.z; acc[6][3] += a1.z * w4.w;
      acc[7][0] += a1.w * w4.x; acc[7][1] += a1.w * w4.y; acc[7][2] += a1.w * w4.z; acc[7][3] += a1.w * w4.w;
    }
    __syncthreads();
  }
#pragma unroll
  for (int i = 0; i < 8; i++) {
    int row = row0 + ty * 8 + i;
    if (row < nrows) {
      ushort4 o;
      o.x = f2b(acc[i][0]); o.y = f2b(acc[i][1]); o.z = f2b(acc[i][2]); o.w = f2b(acc[i][3]);
      *(ushort4*)&Cb[(size_t)row * M + col0 + tx * 4] = o;
    }
  }
  if (a_s) {
    int F = M >> 2;                  // per-head channels (64 or 32)
    int lphl = F >> 2;               // tx lanes per head (16 or 8)
    int gcol = col0 + tx * 4;
    int h = gcol / F;
    int cc = gcol - h * F;
    float4 s4 = *(const float4*)&a_s[h * F + cc];
    float4 d4 = *(const float4*)&a_d[h * F + cc];
#pragma unroll
    for (int i = 0; i < 8; i++) {
      float ps = acc[i][0] * s4.x + acc[i][1] * s4.y + acc[i][2] * s4.z + acc[i][3] * s4.w;
      float pd = acc[i][0] * d4.x + acc[i][1] * d4.y + acc[i][2] * d4.z + acc[i][3] * d4.w;
      for (int mm = 1; mm < lphl; mm <<= 1) { ps += __shfl_xor(ps, mm); pd += __shfl_xor(pd, mm); }
      if ((tx & (lphl - 1)) == 0) {
        int row = row0 + ty * 8 + i;
        if (row < nrows) { als[row * 4 + h] = ps; ald[row * 4 + h] = pd; }
      }
    }
  }
}

// ----------------------------- SAGE aggregate (bf16 gather, fp32 accum) -----------------------
__global__ __launch_bounds__(256) void k_sage_agg(const bfu* __restrict__ hcat,
                                                  const float* __restrict__ bias,
                                                  const int* __restrict__ offsets,
                                                  const int* __restrict__ csr_src,
                                                  float* __restrict__ out, int n, int F) {
  int wave = threadIdx.x >> 6, lane = threadIdx.x & 63;
  int v = blockIdx.x * 4 + wave;
  if (v >= n || lane >= F) return;
  const int st = 2 * F;
  int d0 = offsets[v], d1 = offsets[v + 1];
  float acc = 0.f;
  int e = d0;
  for (; e + 4 <= d1; e += 4) {
    int s0 = csr_src[e], s1 = csr_src[e + 1], s2 = csr_src[e + 2], s3 = csr_src[e + 3];
    float v0 = b2f(hcat[(size_t)s0 * st + lane]);
    float v1 = b2f(hcat[(size_t)s1 * st + lane]);
    float v2 = b2f(hcat[(size_t)s2 * st + lane]);
    float v3 = b2f(hcat[(size_t)s3 * st + lane]);
    acc += (v0 + v1) + (v2 + v3);
  }
  for (; e < d1; ++e) acc += b2f(hcat[(size_t)csr_src[e] * st + lane]);
  int d = d1 - d0;
  float inv = 1.f / (float)(d > 1 ? d : 1);
  float y = acc * inv + bias[lane] + b2f(hcat[(size_t)v * st + F + lane]);
  out[(size_t)v * F + lane] = fmaxf(y, 0.f);
}

// ------------- GAT aggregate: online softmax + weighted sum + bias + relu + head-mean ---------
__global__ __launch_bounds__(256) void k_gat_agg(const bfu* __restrict__ xh,
                                                 const float* __restrict__ als,
                                                 const float* __restrict__ ald,
                                                 const float* __restrict__ bias,
                                                 const int* __restrict__ offsets,
                                                 const int* __restrict__ csr_src,
                                                 float* __restrict__ out, int n, int F) {
  int wave = threadIdx.x >> 6, lane = threadIdx.x & 63;
  int v = blockIdx.x * 4 + wave;
  if (v >= n || lane >= F) return;
  int lph = F >> 2;
  int h = lane / lph;
  int c0 = lane * 4;
  const int st = 4 * F;
  float ad = ald[v * 4 + h];
  int d0 = offsets[v], d1 = offsets[v + 1];
  float m = -1e30f, sum = 0.f;
  float a0 = 0.f, a1 = 0.f, a2 = 0.f, a3 = 0.f;

  auto step = [&](float l, ushort4 xu) {
    float t = l + ad; t = t > 0.f ? t : 0.2f * t;
    float nM = fmaxf(m, t);
    if (nM > m) {
      float r = __expf(m - nM);
      sum *= r; a0 *= r; a1 *= r; a2 *= r; a3 *= r;
      m = nM;
    }
    float p = __expf(t - m);
    sum += p;
    a0 += p * b2f(xu.x); a1 += p * b2f(xu.y); a2 += p * b2f(xu.z); a3 += p * b2f(xu.w);
  };

  int e = d0;
  for (; e + 4 <= d1; e += 4) {
    int s0 = csr_src[e], s1 = csr_src[e + 1], s2 = csr_src[e + 2], s3 = csr_src[e + 3];
    float l0 = als[(size_t)s0 * 4 + h];
    float l1 = als[(size_t)s1 * 4 + h];
    float l2 = als[(size_t)s2 * 4 + h];
    float l3 = als[(size_t)s3 * 4 + h];
    ushort4 x0 = *(const ushort4*)&xh[(size_t)s0 * st + c0];
    ushort4 x1 = *(const ushort4*)&xh[(size_t)s1 * st + c0];
    ushort4 x2 = *(const ushort4*)&xh[(size_t)s2 * st + c0];
    ushort4 x3 = *(const ushort4*)&xh[(size_t)s3 * st + c0];
    step(l0, x0); step(l1, x1); step(l2, x2); step(l3, x3);
  }
  for (; e < d1; ++e) {
    int s = csr_src[e];
    float l = als[(size_t)s * 4 + h];
    ushort4 xu = *(const ushort4*)&xh[(size_t)s * st + c0];
    step(l, xu);
  }

  float inv = 1.f / (sum + 1e-16f);
  a0 *= inv; a1 *= inv; a2 *= inv; a3 *= inv;
  float4 b4 = *(const float4*)&bias[c0];
  a0 = fmaxf(a0 + b4.x, 0.f);
  a1 = fmaxf(a1 + b4.y, 0.f);
  a2 = fmaxf(a2 + b4.z, 0.f);
  a3 = fmaxf(a3 + b4.w, 0.f);
  for (int mm = lph; mm < F; mm <<= 1) {
    a0 += __shfl_xor(a0, mm);
    a1 += __shfl_xor(a1, mm);
    a2 += __shfl_xor(a2, mm);
    a3 += __shfl_xor(a3, mm);
  }
  if (lane < lph) {
    float4 o = make_float4(a0 * 0.25f, a1 * 0.25f, a2 * 0.25f, a3 * 0.25f);
    *(float4*)&out[(size_t)v * F + c0] = o;
  }
}

// ----------------------------- penalty + exp scale + L2 normalize -----------------------------
__global__ __launch_bounds__(256) void k_final(const float* __restrict__ y,
                                               const float* __restrict__ Wp,
                                               const float* __restrict__ bp,
                                               float* __restrict__ out, int n) {
  int wave = threadIdx.x >> 6, lane = threadIdx.x & 63;
  int v = blockIdx.x * 4 + wave;
  if (v >= n || lane >= 32) return;
  float yv = y[(size_t)v * 32 + lane];
  float p = yv * Wp[lane];
  for (int m = 1; m < 32; m <<= 1) p += __shfl_xor(p, m);
  p += bp[0];
  float s = __expf(p);
  float xv = yv * s;
  float q = xv * xv;
  for (int m = 1; m < 32; m <<= 1) q += __shfl_xor(q, m);
  float nrm = sqrtf(q);
  nrm = fmaxf(nrm, 1e-12f);
  out[(size_t)v * 32 + lane] = xv / nrm;
}

// ----------------------------- launch -----------------------------
extern "C" void kernel_launch(void* const* d_in, const int* in_sizes, int n_in,
                              void* d_out, int out_size, void* d_ws, size_t ws_size,
                              hipStream_t stream) {
  (void)in_sizes; (void)n_in; (void)out_size; (void)ws_size;
  const float* x   = (const float*)d_in[0];
  const int*   ei  = (const int*)d_in[1];
  const float* W1l = (const float*)d_in[2];
  const float* b1l = (const float*)d_in[3];
  const float* W1r = (const float*)d_in[4];
  const float* Wa1 = (const float*)d_in[5];
  const float* as1 = (const float*)d_in[6];
  const float* ad1 = (const float*)d_in[7];
  const float* ba1 = (const float*)d_in[8];
  const float* W2l = (const float*)d_in[9];
  const float* b2l = (const float*)d_in[10];
  const float* W2r = (const float*)d_in[11];
  const float* Wa2 = (const float*)d_in[12];
  const float* as2 = (const float*)d_in[13];
  const float* ad2 = (const float*)d_in[14];
  const float* ba2 = (const float*)d_in[15];
  const float* W3l = (const float*)d_in[16];
  const float* b3l = (const float*)d_in[17];
  const float* W3r = (const float*)d_in[18];
  const float* Wa3 = (const float*)d_in[19];
  const float* as3 = (const float*)d_in[20];
  const float* ad3 = (const float*)d_in[21];
  const float* ba3 = (const float*)d_in[22];
  const float* Wp  = (const float*)d_in[23];
  const float* bp  = (const float*)d_in[24];
  float* out = (float*)d_out;

  char* ws = (char*)d_ws;
  size_t off = 0;
  auto alloc = [&](size_t bytes) -> void* {
    void* p = ws + off;
    off += (bytes + 255) & ~(size_t)255;
    return p;
  };
  int* deg    = (int*)alloc((size_t)NNODES * 4);
  int* offs   = (int*)alloc((size_t)(NNODES + 1) * 4);
  int* cursor = (int*)alloc((size_t)NNODES * 4);
  int* csr    = (int*)alloc((size_t)NEDGES * 4);
  int* bsums  = (int*)alloc((size_t)SCAN_BLOCKS * 4);
  float* Wc1  = (float*)alloc((size_t)128 * 128 * 4);
  float* Wc2  = (float*)alloc((size_t)64 * 128 * 4);
  float* Wc3  = (float*)alloc((size_t)64 * 64 * 4);
  bfu* bufA   = (bfu*)alloc((size_t)NNODES * 256 * 2);   // xh (bf16)
  bfu* bufCD  = (bfu*)alloc((size_t)NNODES * 128 * 2);   // [hl|hr] (bf16)
  float* bufB = (float*)alloc((size_t)NNODES * 64 * 4);  // layer io (fp32)
  float* als  = (float*)alloc((size_t)NNODES * 4 * 4);
  float* ald  = (float*)alloc((size_t)NNODES * 4 * 4);

  hipMemsetAsync(deg, 0, (size_t)NNODES * 4, stream);
  hipMemsetAsync(cursor, 0, (size_t)NNODES * 4, stream);
  int eb = (NEDGES + 255) / 256;
  k_hist<<<eb, 256, 0, stream>>>(ei, deg, NEDGES);
  k_pack2<<<(128 * 128 + 255) / 256, 256, 0, stream>>>(W1l, W1r, Wc1, 128, 64);
  k_pack2<<<(64 * 128 + 255) / 256, 256, 0, stream>>>(W2l, W2r, Wc2, 64, 64);
  k_pack2<<<(64 * 64 + 255) / 256, 256, 0, stream>>>(W3l, W3r, Wc3, 64, 32);
  k_scan1<<<SCAN_BLOCKS, 256, 0, stream>>>(deg, bsums, NNODES);
  k_scan2<<<1, 128, 0, stream>>>(bsums, offs, NNODES);
  k_scan3<<<SCAN_BLOCKS, 256, 0, stream>>>(deg, bsums, offs, NNODES);
  k_fill<<<eb, 256, 0, stream>>>(ei, offs, cursor, csr, NEDGES);

  int nb = (NNODES + 3) / 4;
  auto gemm = [&](const float* A, const float* W, bfu* C, int K, int M,
                  const float* asp, const float* adp) {
    dim3 grid((NNODES + 127) / 128, M / 64);
    k_sgemm<<<grid, 256, 0, stream>>>(A, W, C, NNODES, K, M, asp, adp, als, ald);
  };

  // ---- block 1 (in=128, F=64) ----
  gemm(x, Wc1, bufCD, 128, 128, nullptr, nullptr);
  k_sage_agg<<<nb, 256, 0, stream>>>(bufCD, b1l, offs, csr, bufB, NNODES, 64);
  gemm(bufB, Wa1, bufA, 64, 256, as1, ad1);
  k_gat_agg<<<nb, 256, 0, stream>>>(bufA, als, ald, ba1, offs, csr, bufB, NNODES, 64);

  // ---- block 2 (in=64, F=64) ----
  gemm(bufB, Wc2, bufCD, 64, 128, nullptr, nullptr);
  k_sage_agg<<<nb, 256, 0, stream>>>(bufCD, b2l, offs, csr, bufB, NNODES, 64);
  gemm(bufB, Wa2, bufA, 64, 256, as2, ad2);
  k_gat_agg<<<nb, 256, 0, stream>>>(bufA, als, ald, ba2, offs, csr, bufB, NNODES, 64);

  // ---- block 3 (in=64, F=32) ----
  gemm(bufB, Wc3, bufCD, 64, 64, nullptr, nullptr);
  k_sage_agg<<<nb, 256, 0, stream>>>(bufCD, b3l, offs, csr, bufB, NNODES, 32);
  gemm(bufB, Wa3, bufA, 32, 128, as3, ad3);
  k_gat_agg<<<nb, 256, 0, stream>>>(bufA, als, ald, ba3, offs, csr, bufB, NNODES, 32);

  k_final<<<nb, 256, 0, stream>>>(bufB, Wp, bp, out, NNODES);
}